// Round 13
// baseline (63.571 us; speedup 1.0000x reference)
//
#include <hip/hip_runtime.h>

// Problem geometry (fixed by the reference): u is (B=2, C=3, D=160, H=192, W=160) float32.
#define Dd 160
#define Hh 192
#define Ww 160
#define HW (Hh * Ww)                       // 30720
#define DHW ((size_t)Dd * HW)              // 4,915,200
#define NVOX_D 9830400.0                   // 2 * 160*192*160

#define TH 8                                // h-rows per block
#define TD 10                               // d-planes per block (sliding window)
#define QROW (Ww / 4)                       // 40 float4-quads per row
#define TPB (QROW * TH)                     // 320 threads = 5 waves
#define NHT (Hh / TH)                       // 24
#define NDS (Dd / TD)                       // 16
#define GRID1 (2 * NHT * NDS)               // 768 blocks = 3 per CU, 8*96
#define NXCD 8
#define CHUNK (GRID1 / NXCD)                // 96 logical blocks per XCD
#define NWAVE (TPB / 64)                    // 5
#define RBLK 256                            // threads used for the fused final reduce

__device__ __forceinline__ float4 ld4(const float* p) {
    return *reinterpret_cast<const float4*>(p);
}

__device__ __forceinline__ int clampi(int v, int lo, int hi) {
    return (v < lo) ? lo : ((v > hi) ? hi : v);
}

// w-gradient for a quad given its left/right edge scalars (jnp.gradient semantics)
__device__ __forceinline__ float4 wgrad(float4 cc, float lft, float rgt, int w0) {
    float4 g;
    g.x = (w0 == 0)      ? (cc.y - cc.x) : 0.5f * (cc.y - lft);
    g.y = 0.5f * (cc.z - cc.x);
    g.z = 0.5f * (cc.w - cc.y);
    g.w = (w0 + 4 == Ww) ? (cc.w - cc.z) : 0.5f * (rgt - cc.z);
    return g;
}

// relu(-det(J)) for one voxel given the 9 raw (unscaled) finite-difference grads.
__device__ __forceinline__ float relu_negdet(
    float gd0, float gh0, float gw0,
    float gd1, float gh1, float gw1,
    float gd2, float gh2, float gw2)
{
    const float sx = 79.5f;   // (D-1)/2 -> channel 0
    const float sy = 95.5f;   // (H-1)/2 -> channel 1
    const float sz = 79.5f;   // (W-1)/2 -> channel 2
    float dxx = fmaf(sx, gd0, 1.0f);
    float dxy = sx * gh0;
    float dxz = sx * gw0;
    float dyx = sy * gd1;
    float dyy = fmaf(sy, gh1, 1.0f);
    float dyz = sy * gw1;
    float dzx = sz * gd2;
    float dzy = sz * gh2;
    float dzz = fmaf(sz, gw2, 1.0f);
    float det = dxx * (dyy * dzz - dyz * dzy)
              + dxy * (dyz * dzx - dyx * dzz)
              + dxz * (dyx * dzy - dyy * dzx);
    return fmaxf(-det, 0.0f);
}

// R12 champion + fused final reduce (last-block-done, rocPRIM pattern):
//  - 3-plane register window {d-1, d, d+1} fully loaded before step d; step d
//    issues plane d+2's centers (consumed next step). h-neighbors + w-edge
//    scalars stay same-step (L2 hits, covered by 15 waves/CU TLP).
//  - After the block reduce: write partial, __threadfence(), atomicAdd on a
//    counter; the 768th block volatile-reads all partials and does the SAME
//    fixed-order f64 tree -> bit-deterministic, saves the 2nd kernel launch.
__global__ __launch_bounds__(TPB) void jac_fused(const float* __restrict__ u,
                                                 float* __restrict__ part,
                                                 unsigned int* __restrict__ counter,
                                                 float* __restrict__ out)
{
    // bijective XCD-chunked swizzle (768 = 8*96, ds fastest): d-neighbors same XCD
    const int lg  = (blockIdx.x % NXCD) * CHUNK + blockIdx.x / NXCD;
    const int ds  = lg % NDS;
    const int ht  = (lg / NDS) % NHT;
    const int b   = lg / (NDS * NHT);

    const int tid = threadIdx.x;
    const int wq  = tid % QROW;
    const int hh  = tid / QROW;
    const int h   = ht * TH + hh;
    const int w0  = wq * 4;

    // jnp.gradient edge handling via clamped indices (one-sided at h=0/H-1)
    const int hm = (h > 0)      ? h - 1 : 0;
    const int hp = (h < Hh - 1) ? h + 1 : Hh - 1;
    const float hinv = 1.0f / (float)(hp - hm);
    const int offm = (hm - h) * Ww;   // 0 or -Ww
    const int offp = (hp - h) * Ww;   // 0 or +Ww

    const int d0     = ds * TD;
    const int dir    = (ds & 1) ? -1 : 1;              // boustrophedon
    const int dstart = (dir > 0) ? d0 : d0 + TD - 1;

    // channel base pointers at (b, c, d=0, h, w0)
    const float* pcA = u + (size_t)(b * 3 + 0) * DHW + (size_t)h * Ww + w0;
    const float* pcB = pcA + DHW;
    const float* pcC = pcA + 2 * DHW;

    // center-plane pipeline: M = d-1, C = d, P = d+1 (loaded), I = d+2 (in flight)
    float4 aM, aC, aP, aI, bM, bC, bP, bI, cM, cC, cP, cI;
    {
        const size_t om = (size_t)clampi(dstart - dir, 0, Dd - 1) * HW;
        const size_t oc = (size_t)dstart * HW;
        const size_t op = (size_t)clampi(dstart + dir, 0, Dd - 1) * HW;
        aM = ld4(pcA + om);  aC = ld4(pcA + oc);  aP = ld4(pcA + op);
        bM = ld4(pcB + om);  bC = ld4(pcB + oc);  bP = ld4(pcB + op);
        cM = ld4(pcC + om);  cC = ld4(pcC + oc);  cP = ld4(pcC + op);
    }

    float acc = 0.0f;

    #pragma unroll 2
    for (int i = 0; i < TD; ++i) {
        const int d = dstart + dir * i;
        const float dinvs = (float)dir * ((d > 0 && d < Dd - 1) ? 0.5f : 1.0f);
        const size_t od = (size_t)d * HW;

        const float* pdA = pcA + od;
        const float* pdB = pcB + od;
        const float* pdC = pcC + od;

        // 1) same-step short-latency loads: h-neighbor quads + w-edge scalars
        float4 rAm = ld4(pdA + offm), rAp = ld4(pdA + offp);
        float4 rBm = ld4(pdB + offm), rBp = ld4(pdB + offp);
        float4 rCm = ld4(pdC + offm), rCp = ld4(pdC + offp);
        float lA = (w0 > 0) ? pdA[-1] : 0.0f;
        float lB = (w0 > 0) ? pdB[-1] : 0.0f;
        float lC = (w0 > 0) ? pdC[-1] : 0.0f;
        float rA = (w0 + 4 < Ww) ? pdA[4] : 0.0f;
        float rB = (w0 + 4 < Ww) ? pdB[4] : 0.0f;
        float rC = (w0 + 4 < Ww) ? pdC[4] : 0.0f;

        // 2) issue NEXT-next plane centers (d + 2*dir), consumed next iteration
        {
            const size_t oi = (size_t)clampi(d + 2 * dir, 0, Dd - 1) * HW;
            aI = ld4(pcA + oi);
            bI = ld4(pcB + oi);
            cI = ld4(pcC + oi);
        }

        // 3) compute plane d; gd reads ONLY registers (aM/aP loaded >= 1 step ago)
        float4 gwA = wgrad(aC, lA, rA, w0);
        float4 gwB = wgrad(bC, lB, rB, w0);
        float4 gwC = wgrad(cC, lC, rC, w0);

        float4 ghA = make_float4((rAp.x - rAm.x) * hinv, (rAp.y - rAm.y) * hinv,
                                 (rAp.z - rAm.z) * hinv, (rAp.w - rAm.w) * hinv);
        float4 ghB = make_float4((rBp.x - rBm.x) * hinv, (rBp.y - rBm.y) * hinv,
                                 (rBp.z - rBm.z) * hinv, (rBp.w - rBm.w) * hinv);
        float4 ghC = make_float4((rCp.x - rCm.x) * hinv, (rCp.y - rCm.y) * hinv,
                                 (rCp.z - rCm.z) * hinv, (rCp.w - rCm.w) * hinv);

        float4 gdA = make_float4((aP.x - aM.x) * dinvs, (aP.y - aM.y) * dinvs,
                                 (aP.z - aM.z) * dinvs, (aP.w - aM.w) * dinvs);
        float4 gdB = make_float4((bP.x - bM.x) * dinvs, (bP.y - bM.y) * dinvs,
                                 (bP.z - bM.z) * dinvs, (bP.w - bM.w) * dinvs);
        float4 gdC = make_float4((cP.x - cM.x) * dinvs, (cP.y - cM.y) * dinvs,
                                 (cP.z - cM.z) * dinvs, (cP.w - cM.w) * dinvs);

        acc += relu_negdet(gdA.x, ghA.x, gwA.x, gdB.x, ghB.x, gwB.x, gdC.x, ghC.x, gwC.x)
             + relu_negdet(gdA.y, ghA.y, gwA.y, gdB.y, ghB.y, gwB.y, gdC.y, ghC.y, gwC.y)
             + relu_negdet(gdA.z, ghA.z, gwA.z, gdB.z, ghB.z, gwB.z, gdC.z, ghC.z, gwC.z)
             + relu_negdet(gdA.w, ghA.w, gwA.w, gdB.w, ghB.w, gwB.w, gdC.w, ghC.w, gwC.w);

        // 4) slide the pipeline (the wait on aI/bI/cI lands next iteration)
        aM = aC; aC = aP; aP = aI;
        bM = bC; bC = bP; bP = bI;
        cM = cC; cC = cP; cP = cI;
    }

    // deterministic block reduction: wave64 shuffle tree, then 5-word LDS
    #pragma unroll
    for (int off = 32; off > 0; off >>= 1)
        acc += __shfl_down(acc, off, 64);
    __shared__ float sred[NWAVE];
    __shared__ int lastFlag;
    const int lane = tid & 63;
    const int wid  = tid >> 6;
    if (lane == 0) sred[wid] = acc;
    __syncthreads();

    // publish partial; last-arriving block performs the final reduce
    if (tid == 0) {
        part[lg] = ((sred[0] + sred[1]) + (sred[2] + sred[3])) + sred[4];
        __threadfence();                                   // device-scope: cross-XCD visible
        unsigned int old = atomicAdd(counter, 1u);         // device-scope by default
        lastFlag = (old == (unsigned int)(GRID1 - 1)) ? 1 : 0;
    }
    __syncthreads();

    if (lastFlag) {
        // 768 partials -> mean, fixed-order f64 tree (bit-deterministic;
        // identical to the old jac_final). volatile reads bypass stale L1.
        __shared__ double s[RBLK];
        if (tid < RBLK) {
            volatile const float* vp = part;
            s[tid] = (double)vp[tid] + (double)vp[tid + 256] + (double)vp[tid + 512];
        }
        __syncthreads();
        #pragma unroll
        for (int off = RBLK / 2; off > 0; off >>= 1) {
            if (tid < off) s[tid] += s[tid + off];
            __syncthreads();
        }
        if (tid == 0)
            out[0] = (float)(s[0] / NVOX_D);
    }
}

extern "C" void kernel_launch(void* const* d_in, const int* in_sizes, int n_in,
                              void* d_out, int out_size, void* d_ws, size_t ws_size,
                              hipStream_t stream)
{
    const float* u = (const float*)d_in[0];
    unsigned int* counter = (unsigned int*)d_ws;           // [0,256): counter
    float* part = (float*)((char*)d_ws + 256);             // 768 floats

    // zero the arrival counter every call (graph-capture-safe async memset)
    hipMemsetAsync(d_ws, 0, 256, stream);
    jac_fused<<<GRID1, TPB, 0, stream>>>(u, part, counter, (float*)d_out);
}

// Round 14
// 37.311 us; speedup vs baseline: 1.7038x; 1.7038x over previous
//
#include <hip/hip_runtime.h>

// Problem geometry (fixed by the reference): u is (B=2, C=3, D=160, H=192, W=160) float32.
#define Dd 160
#define Hh 192
#define Ww 160
#define HW (Hh * Ww)                       // 30720
#define DHW ((size_t)Dd * HW)              // 4,915,200
#define NVOX_D 9830400.0                   // 2 * 160*192*160

#define TH 8                                // h-rows per block
#define TD 10                               // d-planes per block (sliding window)
#define QROW (Ww / 4)                       // 40 float4-quads per row
#define TPB (QROW * TH)                     // 320 threads = 5 waves
#define NHT (Hh / TH)                       // 24
#define NDS (Dd / TD)                       // 16
#define GRID1 (2 * NHT * NDS)               // 768 blocks = 3 per CU, 8*96
#define NXCD 8
#define CHUNK (GRID1 / NXCD)                // 96 logical blocks per XCD
#define NWAVE (TPB / 64)                    // 5
#define BLK2 256

__device__ __forceinline__ float4 ld4(const float* p) {
    return *reinterpret_cast<const float4*>(p);
}

__device__ __forceinline__ int clampi(int v, int lo, int hi) {
    return (v < lo) ? lo : ((v > hi) ? hi : v);
}

// w-gradient for a quad given its left/right edge scalars (jnp.gradient semantics)
__device__ __forceinline__ float4 wgrad(float4 cc, float lft, float rgt, int w0) {
    float4 g;
    g.x = (w0 == 0)      ? (cc.y - cc.x) : 0.5f * (cc.y - lft);
    g.y = 0.5f * (cc.z - cc.x);
    g.z = 0.5f * (cc.w - cc.y);
    g.w = (w0 + 4 == Ww) ? (cc.w - cc.z) : 0.5f * (rgt - cc.z);
    return g;
}

// relu(-det(J)) for one voxel given the 9 raw (unscaled) finite-difference grads.
__device__ __forceinline__ float relu_negdet(
    float gd0, float gh0, float gw0,
    float gd1, float gh1, float gw1,
    float gd2, float gh2, float gw2)
{
    const float sx = 79.5f;   // (D-1)/2 -> channel 0
    const float sy = 95.5f;   // (H-1)/2 -> channel 1
    const float sz = 79.5f;   // (W-1)/2 -> channel 2
    float dxx = fmaf(sx, gd0, 1.0f);
    float dxy = sx * gh0;
    float dxz = sx * gw0;
    float dyx = sy * gd1;
    float dyy = fmaf(sy, gh1, 1.0f);
    float dyz = sy * gw1;
    float dzx = sz * gd2;
    float dzy = sz * gh2;
    float dzz = fmaf(sz, gw2, 1.0f);
    float det = dxx * (dyy * dzz - dyz * dzy)
              + dxy * (dyz * dzx - dyx * dzz)
              + dxz * (dyx * dzy - dyy * dzx);
    return fmaxf(-det, 0.0f);
}

// Champion structure (R12):
//  - 3-plane register window {d-1, d, d+1} is FULLY loaded before step d runs;
//    step d issues plane d+2's centers (consumed next step). The long-latency
//    (L3/HBM) loads thus get a full step of compute x 15 waves/CU of cover.
//  - h-neighbor quads + w-edge scalars stay same-step: they are L1/L2 hits
//    (siblings loaded those rows as centers one step earlier).
//  - XCD-chunked bijective swizzle + boustrophedon d-march for L2 phase locality.
//  - Separate tiny reduce kernel: fusing it needs a device-scope fence per
//    block, which flushes per-XCD L2 and poisons the main loop (R13: +26 us).
__global__ __launch_bounds__(TPB) void jac_partial(const float* __restrict__ u,
                                                   float* __restrict__ part)
{
    // bijective XCD-chunked swizzle (768 = 8*96, ds fastest): d-neighbors same XCD
    const int lg  = (blockIdx.x % NXCD) * CHUNK + blockIdx.x / NXCD;
    const int ds  = lg % NDS;
    const int ht  = (lg / NDS) % NHT;
    const int b   = lg / (NDS * NHT);

    const int tid = threadIdx.x;
    const int wq  = tid % QROW;
    const int hh  = tid / QROW;
    const int h   = ht * TH + hh;
    const int w0  = wq * 4;

    // jnp.gradient edge handling via clamped indices (one-sided at h=0/H-1)
    const int hm = (h > 0)      ? h - 1 : 0;
    const int hp = (h < Hh - 1) ? h + 1 : Hh - 1;
    const float hinv = 1.0f / (float)(hp - hm);
    const int offm = (hm - h) * Ww;   // 0 or -Ww
    const int offp = (hp - h) * Ww;   // 0 or +Ww

    const int d0     = ds * TD;
    const int dir    = (ds & 1) ? -1 : 1;              // boustrophedon
    const int dstart = (dir > 0) ? d0 : d0 + TD - 1;

    // channel base pointers at (b, c, d=0, h, w0)
    const float* pcA = u + (size_t)(b * 3 + 0) * DHW + (size_t)h * Ww + w0;
    const float* pcB = pcA + DHW;
    const float* pcC = pcA + 2 * DHW;

    // center-plane pipeline: M = d-1, C = d, P = d+1 (loaded), I = d+2 (in flight)
    float4 aM, aC, aP, aI, bM, bC, bP, bI, cM, cC, cP, cI;
    {
        const size_t om = (size_t)clampi(dstart - dir, 0, Dd - 1) * HW;
        const size_t oc = (size_t)dstart * HW;
        const size_t op = (size_t)clampi(dstart + dir, 0, Dd - 1) * HW;
        aM = ld4(pcA + om);  aC = ld4(pcA + oc);  aP = ld4(pcA + op);
        bM = ld4(pcB + om);  bC = ld4(pcB + oc);  bP = ld4(pcB + op);
        cM = ld4(pcC + om);  cC = ld4(pcC + oc);  cP = ld4(pcC + op);
    }

    float acc = 0.0f;

    #pragma unroll 2
    for (int i = 0; i < TD; ++i) {
        const int d = dstart + dir * i;
        const float dinvs = (float)dir * ((d > 0 && d < Dd - 1) ? 0.5f : 1.0f);
        const size_t od = (size_t)d * HW;

        const float* pdA = pcA + od;
        const float* pdB = pcB + od;
        const float* pdC = pcC + od;

        // 1) same-step short-latency loads: h-neighbor quads + w-edge scalars
        float4 rAm = ld4(pdA + offm), rAp = ld4(pdA + offp);
        float4 rBm = ld4(pdB + offm), rBp = ld4(pdB + offp);
        float4 rCm = ld4(pdC + offm), rCp = ld4(pdC + offp);
        float lA = (w0 > 0) ? pdA[-1] : 0.0f;
        float lB = (w0 > 0) ? pdB[-1] : 0.0f;
        float lC = (w0 > 0) ? pdC[-1] : 0.0f;
        float rA = (w0 + 4 < Ww) ? pdA[4] : 0.0f;
        float rB = (w0 + 4 < Ww) ? pdB[4] : 0.0f;
        float rC = (w0 + 4 < Ww) ? pdC[4] : 0.0f;

        // 2) issue NEXT-next plane centers (d + 2*dir), consumed next iteration
        {
            const size_t oi = (size_t)clampi(d + 2 * dir, 0, Dd - 1) * HW;
            aI = ld4(pcA + oi);
            bI = ld4(pcB + oi);
            cI = ld4(pcC + oi);
        }

        // 3) compute plane d; gd reads ONLY registers (aM/aP loaded >= 1 step ago)
        float4 gwA = wgrad(aC, lA, rA, w0);
        float4 gwB = wgrad(bC, lB, rB, w0);
        float4 gwC = wgrad(cC, lC, rC, w0);

        float4 ghA = make_float4((rAp.x - rAm.x) * hinv, (rAp.y - rAm.y) * hinv,
                                 (rAp.z - rAm.z) * hinv, (rAp.w - rAm.w) * hinv);
        float4 ghB = make_float4((rBp.x - rBm.x) * hinv, (rBp.y - rBm.y) * hinv,
                                 (rBp.z - rBm.z) * hinv, (rBp.w - rBm.w) * hinv);
        float4 ghC = make_float4((rCp.x - rCm.x) * hinv, (rCp.y - rCm.y) * hinv,
                                 (rCp.z - rCm.z) * hinv, (rCp.w - rCm.w) * hinv);

        float4 gdA = make_float4((aP.x - aM.x) * dinvs, (aP.y - aM.y) * dinvs,
                                 (aP.z - aM.z) * dinvs, (aP.w - aM.w) * dinvs);
        float4 gdB = make_float4((bP.x - bM.x) * dinvs, (bP.y - bM.y) * dinvs,
                                 (bP.z - bM.z) * dinvs, (bP.w - bM.w) * dinvs);
        float4 gdC = make_float4((cP.x - cM.x) * dinvs, (cP.y - cM.y) * dinvs,
                                 (cP.z - cM.z) * dinvs, (cP.w - cM.w) * dinvs);

        acc += relu_negdet(gdA.x, ghA.x, gwA.x, gdB.x, ghB.x, gwB.x, gdC.x, ghC.x, gwC.x)
             + relu_negdet(gdA.y, ghA.y, gwA.y, gdB.y, ghB.y, gwB.y, gdC.y, ghC.y, gwC.y)
             + relu_negdet(gdA.z, ghA.z, gwA.z, gdB.z, ghB.z, gwB.z, gdC.z, ghC.z, gwC.z)
             + relu_negdet(gdA.w, ghA.w, gwA.w, gdB.w, ghB.w, gwB.w, gdC.w, ghC.w, gwC.w);

        // 4) slide the pipeline (the wait on aI/bI/cI lands next iteration)
        aM = aC; aC = aP; aP = aI;
        bM = bC; bC = bP; bP = bI;
        cM = cC; cC = cP; cP = cI;
    }

    // deterministic block reduction: wave64 shuffle tree, then 5-word LDS
    #pragma unroll
    for (int off = 32; off > 0; off >>= 1)
        acc += __shfl_down(acc, off, 64);
    __shared__ float sred[NWAVE];
    const int lane = tid & 63;
    const int wid  = tid >> 6;
    if (lane == 0) sred[wid] = acc;
    __syncthreads();
    if (tid == 0)
        part[lg] = ((sred[0] + sred[1]) + (sred[2] + sred[3])) + sred[4];
}

// 768 partials -> mean. 3 independent loads per thread, f64 fixed-tree reduce
// (deterministic; f64 kills the ~2e8-magnitude sum's rounding concern).
__global__ __launch_bounds__(BLK2) void jac_final(const float* __restrict__ part,
                                                  float* __restrict__ out)
{
    const int t = threadIdx.x;
    double a = (double)part[t] + (double)part[t + 256] + (double)part[t + 512];
    __shared__ double s[BLK2];
    s[t] = a;
    __syncthreads();
    #pragma unroll
    for (int off = BLK2 / 2; off > 0; off >>= 1) {
        if (t < off) s[t] += s[t + off];
        __syncthreads();
    }
    if (t == 0)
        out[0] = (float)(s[0] / NVOX_D);
}

extern "C" void kernel_launch(void* const* d_in, const int* in_sizes, int n_in,
                              void* d_out, int out_size, void* d_ws, size_t ws_size,
                              hipStream_t stream)
{
    const float* u = (const float*)d_in[0];
    float* part = (float*)d_ws;              // 768 floats = 3 KB of scratch

    jac_partial<<<GRID1, TPB, 0, stream>>>(u, part);
    jac_final<<<1, BLK2, 0, stream>>>(part, (float*)d_out);
}